// Round 22
// baseline (290.210 us; speedup 1.0000x reference)
//
#include <hip/hip_runtime.h>
#include <math.h>

#define NROWS 64
#define DCOLS 512
#define HCOL  256
#define BDIM  512
#define NWV   8     // waves per block
#define RPW   8     // rows per wave; one batch per block, grid = 4096

typedef float f32x4 __attribute__((ext_vector_type(4)));
typedef unsigned short u16x4 __attribute__((ext_vector_type(4)));

__device__ __forceinline__ void wave_reduce_sum2(float& a, float& b) {
#pragma unroll
    for (int off = 32; off > 0; off >>= 1) {
        a += __shfl_xor(a, off, 64);
        b += __shfl_xor(b, off, 64);
    }
}
__device__ __forceinline__ float wave_reduce_sum(float v) {
#pragma unroll
    for (int off = 32; off > 0; off >>= 1)
        v += __shfl_xor(v, off, 64);
    return v;
}

__device__ __forceinline__ float hsum8(f32x4 a, f32x4 b) {
    return ((a.x + a.y) + (a.z + a.w)) + ((b.x + b.y) + (b.z + b.w));
}
__device__ __forceinline__ float hsumsq8(f32x4 a, f32x4 b) {
    return (a.x*a.x + a.y*a.y + a.z*a.z + a.w*a.w)
         + (b.x*b.x + b.y*b.y + b.z*b.z + b.w*b.w);
}

// tanh(x) = 1 - 2/(exp(2x)+1); correct both signs, saturates at +/-1.
__device__ __forceinline__ float fast_tanh(float x) {
    float e = __expf(2.0f * x);
    return 1.0f - 2.0f / (e + 1.0f);
}

// bf16 pack/unpack (RNE)
__device__ __forceinline__ unsigned short f2b(float f) {
    union { float f; unsigned int u; } v; v.f = f;
    unsigned int r = (v.u + 0x7FFFu + ((v.u >> 16) & 1u)) >> 16;
    return (unsigned short)r;
}
__device__ __forceinline__ float b2f(unsigned short h) {
    union { unsigned int u; float f; } v; v.u = ((unsigned int)h) << 16;
    return v.f;
}

// LDS-ordering barrier: does NOT drain vmcnt.
__device__ __forceinline__ void lds_barrier() {
    asm volatile("s_waitcnt lgkmcnt(0)" ::: "memory");
    __builtin_amdgcn_s_barrier();
}

__global__ __launch_bounds__(BDIM, 6) void fused_ln_attn_kernel(
    const float* __restrict__ emb,
    const float* __restrict__ gamma,
    const float* __restrict__ beta,
    const float* __restrict__ Wv,
    const float* __restrict__ bv,
    float* __restrict__ out)
{
    // ~37.2 KiB LDS; launch_bounds(512,6) -> 85-VGPR cap -> 3 blocks/CU
    // (24 waves): 3 independent barrier domains, ONE working barrier each.
    __shared__ unsigned short      s_e1[NROWS * HCOL];  // 32 KiB, bf16 e1
    __shared__ __align__(16) float s_g[DCOLS];
    __shared__ __align__(16) float s_b[DCOLS];
    __shared__ unsigned short      s_w[DCOLS];          // bf16 Wv
    __shared__ float s_den[NWV];

    const int tid  = threadIdx.x;
    const int wave = tid >> 6;
    const int lane = tid & 63;
    const int c0   = lane << 2;
    const int c1   = HCOL + c0;
    const int r0   = wave * RPW;

    s_g[tid] = gamma[tid];
    s_b[tid] = beta[tid];
    s_w[tid] = f2b(Wv[tid]);
    const float bias = bv[0];

    const size_t base = (size_t)blockIdx.x * (size_t)(NROWS * DCOLS);
    const float* eb = emb + base;
    float*       ob = out + base;

    // row-0 x: issued before the params barrier; L1/L2-hot broadcast lines
    const f32x4 qxa = *(const f32x4*)(eb + c0);
    const f32x4 qxb = *(const f32x4*)(eb + c1);

    lds_barrier();   // params visible (once per kernel)

    const f32x4 g0 = *(const f32x4*)(s_g + c0);
    const f32x4 g1 = *(const f32x4*)(s_g + c1);
    const f32x4 b0 = *(const f32x4*)(s_b + c0);
    const f32x4 b1 = *(const f32x4*)(s_b + c1);
    f32x4 w0, w1;
    {
        const u16x4 wa = *(const u16x4*)(s_w + c0);
        const u16x4 wb = *(const u16x4*)(s_w + c1);
        w0.x = b2f(wa.x); w0.y = b2f(wa.y); w0.z = b2f(wa.z); w0.w = b2f(wa.w);
        w1.x = b2f(wb.x); w1.y = b2f(wb.y); w1.z = b2f(wb.z); w1.w = b2f(wb.w);
    }

    // ---- q: EVERY wave computes it redundantly (identical inputs + op
    //      order -> identical result; overlaps the 16 row loads in flight) ----
    f32x4 q0, q1;
    {
        float s = hsum8(qxa, qxb), ss = hsumsq8(qxa, qxb);
        wave_reduce_sum2(s, ss);
        const float mu  = s * (1.0f / (float)DCOLS);
        const float var = ss * (1.0f / (float)DCOLS) - mu * mu;
        const float rs  = rsqrtf(var + 1e-5f);
        q0 = (qxa - mu) * rs * g0 + b0;
        q1 = (qxb - mu) * rs * g1 + b1;
    }

    // ---- Fused pass: LN + score per own row (e1 scored in fp32 regs,
    //      stored bf16 to own LDS slot for pass 3) ----
    f32x4 e0[RPW];
    float ex[RPW];
    float denw = 0.0f;
#pragma unroll
    for (int i = 0; i < RPW; ++i) {
        const int r = r0 + i;
        const f32x4 x0 = *(const f32x4*)(eb + r * DCOLS + c0);
        const f32x4 x1 = *(const f32x4*)(eb + r * DCOLS + c1);

        float s = hsum8(x0, x1), ss = hsumsq8(x0, x1);
        wave_reduce_sum2(s, ss);

        const float mu  = s * (1.0f / (float)DCOLS);
        const float var = ss * (1.0f / (float)DCOLS) - mu * mu;
        const float rs  = rsqrtf(var + 1e-5f);

        e0[i] = (x0 - mu) * rs * g0 + b0;
        const f32x4 t1 = (x1 - mu) * rs * g1 + b1;

        u16x4 pk;
        pk.x = f2b(t1.x); pk.y = f2b(t1.y); pk.z = f2b(t1.z); pk.w = f2b(t1.w);
        *(u16x4*)(s_e1 + r * HCOL + c0) = pk;   // own slot (thread-private)

        float p;
        p  = fast_tanh(q0.x * e0[i].x) * w0.x;
        p += fast_tanh(q0.y * e0[i].y) * w0.y;
        p += fast_tanh(q0.z * e0[i].z) * w0.z;
        p += fast_tanh(q0.w * e0[i].w) * w0.w;
        p += fast_tanh(q1.x * t1.x) * w1.x;
        p += fast_tanh(q1.y * t1.y) * w1.y;
        p += fast_tanh(q1.z * t1.z) * w1.z;
        p += fast_tanh(q1.w * t1.w) * w1.w;
        const float tot = wave_reduce_sum(p) + bias;
        const float e   = __expf(tot);   // max-free: |tot| <= sum|Wv|+|bv| ~ 18
        ex[i] = (r == 0) ? 0.0f : e;
        denw += ex[i];
    }
    if (lane == 0) s_den[wave] = denw;

    lds_barrier();   // the ONLY working barrier: partial denominators

    float den = 0.0f;
#pragma unroll
    for (int w = 0; w < NWV; ++w) den += s_den[w];   // broadcast reads
    const float inv = 1.0f / den;

    // ---- Pass 3: scale + store (row 0 from q regs, a=1) ----
#pragma unroll
    for (int i = 0; i < RPW; ++i) {
        const int r = r0 + i;
        if (r == 0) {
            __builtin_nontemporal_store(q0, (f32x4*)(ob + c0));
            __builtin_nontemporal_store(q1, (f32x4*)(ob + c1));
            continue;   // wave-uniform (wave 0, i==0 only)
        }
        const float a = ex[i] * inv;
        const u16x4 pe = *(const u16x4*)(s_e1 + r * HCOL + c0);
        f32x4 e1;
        e1.x = b2f(pe.x); e1.y = b2f(pe.y); e1.z = b2f(pe.z); e1.w = b2f(pe.w);
        __builtin_nontemporal_store(e0[i] * a, (f32x4*)(ob + r * DCOLS + c0));
        __builtin_nontemporal_store(e1 * a,    (f32x4*)(ob + r * DCOLS + c1));
    }
}

extern "C" void kernel_launch(void* const* d_in, const int* in_sizes, int n_in,
                              void* d_out, int out_size, void* d_ws, size_t ws_size,
                              hipStream_t stream) {
    const float* emb   = (const float*)d_in[0];
    const float* gamma = (const float*)d_in[1];
    const float* beta  = (const float*)d_in[2];
    const float* Wv    = (const float*)d_in[3];
    const float* bv    = (const float*)d_in[4];
    float* out = (float*)d_out;

    const int B = in_sizes[0] / (NROWS * DCOLS);
    fused_ln_attn_kernel<<<B, BDIM, 0, stream>>>(emb, gamma, beta, Wv, bv, out);
}

// Round 23
// 198.769 us; speedup vs baseline: 1.4600x; 1.4600x over previous
//
#include <hip/hip_runtime.h>
#include <math.h>

#define NROWS 64
#define DCOLS 512
#define HCOL  256
#define BDIM  512
#define NWV   8     // waves per block
#define RPW   8     // rows per wave; one batch per block, grid = 4096

typedef float f32x4 __attribute__((ext_vector_type(4)));
typedef unsigned short u16x4 __attribute__((ext_vector_type(4)));

__device__ __forceinline__ void wave_reduce_sum2(float& a, float& b) {
#pragma unroll
    for (int off = 32; off > 0; off >>= 1) {
        a += __shfl_xor(a, off, 64);
        b += __shfl_xor(b, off, 64);
    }
}
__device__ __forceinline__ float wave_reduce_sum(float v) {
#pragma unroll
    for (int off = 32; off > 0; off >>= 1)
        v += __shfl_xor(v, off, 64);
    return v;
}

__device__ __forceinline__ float hsum8(f32x4 a, f32x4 b) {
    return ((a.x + a.y) + (a.z + a.w)) + ((b.x + b.y) + (b.z + b.w));
}
__device__ __forceinline__ float hsumsq8(f32x4 a, f32x4 b) {
    return (a.x*a.x + a.y*a.y + a.z*a.z + a.w*a.w)
         + (b.x*b.x + b.y*b.y + b.z*b.z + b.w*b.w);
}

// tanh(x) = 1 - 2/(exp(2x)+1); correct both signs, saturates at +/-1.
__device__ __forceinline__ float fast_tanh(float x) {
    float e = __expf(2.0f * x);
    return 1.0f - 2.0f / (e + 1.0f);
}

// bf16 pack/unpack (RNE)
__device__ __forceinline__ unsigned short f2b(float f) {
    union { float f; unsigned int u; } v; v.f = f;
    unsigned int r = (v.u + 0x7FFFu + ((v.u >> 16) & 1u)) >> 16;
    return (unsigned short)r;
}
__device__ __forceinline__ float b2f(unsigned short h) {
    union { unsigned int u; float f; } v; v.u = ((unsigned int)h) << 16;
    return v.f;
}

// LDS-ordering barrier: does NOT drain vmcnt.
__device__ __forceinline__ void lds_barrier() {
    asm volatile("s_waitcnt lgkmcnt(0)" ::: "memory");
    __builtin_amdgcn_s_barrier();
}

__global__ __launch_bounds__(BDIM, 4) void fused_ln_attn_kernel(
    const float* __restrict__ emb,
    const float* __restrict__ gamma,
    const float* __restrict__ beta,
    const float* __restrict__ Wv,
    const float* __restrict__ bv,
    float* __restrict__ out)
{
    // ~37.2 KiB LDS; launch_bounds(512,4) -> 128-VGPR tier (the ONLY cap
    // that never spills on this toolchain: R3/R7/R10/R16 evidence). At the
    // ~75-reg actual liveness the HW fits 6 waves/SIMD -> 3 blocks/CU.
    __shared__ unsigned short      s_e1[NROWS * HCOL];  // 32 KiB, bf16 e1
    __shared__ __align__(16) float s_g[DCOLS];
    __shared__ __align__(16) float s_b[DCOLS];
    __shared__ unsigned short      s_w[DCOLS];          // bf16 Wv
    __shared__ float s_den[NWV];

    const int tid  = threadIdx.x;
    const int wave = tid >> 6;
    const int lane = tid & 63;
    const int c0   = lane << 2;
    const int c1   = HCOL + c0;
    const int r0   = wave * RPW;

    s_g[tid] = gamma[tid];
    s_b[tid] = beta[tid];
    s_w[tid] = f2b(Wv[tid]);
    const float bias = bv[0];

    const size_t base = (size_t)blockIdx.x * (size_t)(NROWS * DCOLS);
    const float* eb = emb + base;
    float*       ob = out + base;

    // row-0 x: issued before the params barrier; L1/L2-hot broadcast lines
    const f32x4 qxa = *(const f32x4*)(eb + c0);
    const f32x4 qxb = *(const f32x4*)(eb + c1);

    lds_barrier();   // params visible (once per kernel)

    const f32x4 g0 = *(const f32x4*)(s_g + c0);
    const f32x4 g1 = *(const f32x4*)(s_g + c1);
    const f32x4 b0 = *(const f32x4*)(s_b + c0);
    const f32x4 b1 = *(const f32x4*)(s_b + c1);
    f32x4 w0, w1;
    {
        const u16x4 wa = *(const u16x4*)(s_w + c0);
        const u16x4 wb = *(const u16x4*)(s_w + c1);
        w0.x = b2f(wa.x); w0.y = b2f(wa.y); w0.z = b2f(wa.z); w0.w = b2f(wa.w);
        w1.x = b2f(wb.x); w1.y = b2f(wb.y); w1.z = b2f(wb.z); w1.w = b2f(wb.w);
    }

    // ---- q: EVERY wave computes it redundantly (identical inputs + op
    //      order -> identical result; overlaps the 16 row loads in flight) ----
    f32x4 q0, q1;
    {
        float s = hsum8(qxa, qxb), ss = hsumsq8(qxa, qxb);
        wave_reduce_sum2(s, ss);
        const float mu  = s * (1.0f / (float)DCOLS);
        const float var = ss * (1.0f / (float)DCOLS) - mu * mu;
        const float rs  = rsqrtf(var + 1e-5f);
        q0 = (qxa - mu) * rs * g0 + b0;
        q1 = (qxb - mu) * rs * g1 + b1;
    }

    // ---- Fused pass: LN + score per own row (scored in fp32 regs,
    //      e1 stored bf16 to own LDS slot for pass 3) ----
    f32x4 e0[RPW];
    float ex[RPW];
    float denw = 0.0f;
#pragma unroll
    for (int i = 0; i < RPW; ++i) {
        const int r = r0 + i;
        const f32x4 x0 = *(const f32x4*)(eb + r * DCOLS + c0);
        const f32x4 x1 = *(const f32x4*)(eb + r * DCOLS + c1);

        float s = hsum8(x0, x1), ss = hsumsq8(x0, x1);
        wave_reduce_sum2(s, ss);

        const float mu  = s * (1.0f / (float)DCOLS);
        const float var = ss * (1.0f / (float)DCOLS) - mu * mu;
        const float rs  = rsqrtf(var + 1e-5f);

        e0[i] = (x0 - mu) * rs * g0 + b0;
        const f32x4 t1 = (x1 - mu) * rs * g1 + b1;

        u16x4 pk;
        pk.x = f2b(t1.x); pk.y = f2b(t1.y); pk.z = f2b(t1.z); pk.w = f2b(t1.w);
        *(u16x4*)(s_e1 + r * HCOL + c0) = pk;   // own slot (thread-private)

        float p;
        p  = fast_tanh(q0.x * e0[i].x) * w0.x;
        p += fast_tanh(q0.y * e0[i].y) * w0.y;
        p += fast_tanh(q0.z * e0[i].z) * w0.z;
        p += fast_tanh(q0.w * e0[i].w) * w0.w;
        p += fast_tanh(q1.x * t1.x) * w1.x;
        p += fast_tanh(q1.y * t1.y) * w1.y;
        p += fast_tanh(q1.z * t1.z) * w1.z;
        p += fast_tanh(q1.w * t1.w) * w1.w;
        const float tot = wave_reduce_sum(p) + bias;
        const float e   = __expf(tot);   // max-free: |tot| <= sum|Wv|+|bv| ~ 18
        ex[i] = (r == 0) ? 0.0f : e;
        denw += ex[i];
    }
    if (lane == 0) s_den[wave] = denw;

    lds_barrier();   // the ONLY working barrier: partial denominators

    float den = 0.0f;
#pragma unroll
    for (int w = 0; w < NWV; ++w) den += s_den[w];   // broadcast reads
    const float inv = 1.0f / den;

    // ---- Pass 3: scale + store (row 0 from q regs, a=1) ----
#pragma unroll
    for (int i = 0; i < RPW; ++i) {
        const int r = r0 + i;
        if (r == 0) {
            __builtin_nontemporal_store(q0, (f32x4*)(ob + c0));
            __builtin_nontemporal_store(q1, (f32x4*)(ob + c1));
            continue;   // wave-uniform (wave 0, i==0 only)
        }
        const float a = ex[i] * inv;
        const u16x4 pe = *(const u16x4*)(s_e1 + r * HCOL + c0);
        f32x4 e1;
        e1.x = b2f(pe.x); e1.y = b2f(pe.y); e1.z = b2f(pe.z); e1.w = b2f(pe.w);
        __builtin_nontemporal_store(e0[i] * a, (f32x4*)(ob + r * DCOLS + c0));
        __builtin_nontemporal_store(e1 * a,    (f32x4*)(ob + r * DCOLS + c1));
    }
}

extern "C" void kernel_launch(void* const* d_in, const int* in_sizes, int n_in,
                              void* d_out, int out_size, void* d_ws, size_t ws_size,
                              hipStream_t stream) {
    const float* emb   = (const float*)d_in[0];
    const float* gamma = (const float*)d_in[1];
    const float* beta  = (const float*)d_in[2];
    const float* Wv    = (const float*)d_in[3];
    const float* bv    = (const float*)d_in[4];
    float* out = (float*)d_out;

    const int B = in_sizes[0] / (NROWS * DCOLS);
    fused_ln_attn_kernel<<<B, BDIM, 0, stream>>>(emb, gamma, beta, Wv, bv, out);
}